// Round 7
// baseline (441.011 us; speedup 1.0000x reference)
//
#include <hip/hip_runtime.h>
#include <math.h>

#define BB 64
#define NN 8732
#define CC 81
#define STRIP 32                        // rows per wave
#define GPW 8                           // groups of 4 rows per wave
#define CWAVES ((NN + STRIP - 1) / STRIP)        // 273 conf waves per batch
#define CBX ((CWAVES + 3) / 4)          // 69 conf blocks per batch
#define LBX 5                           // loc blocks per batch

// ---------------- init: zero per-b accumulators + output ----------------
__global__ void init_kernel(unsigned* acc, float* out) {
    int i = threadIdx.x;
    if (i < 4 * BB) acc[i] = 0u;   // num_pos[B], pos_sum[B], loc_cnt[B], loc_sum[B]
    if (i == 0) out[0] = 0.f;
}

// ---------------- fused conf + loc: direct-load, no LDS conf path ----------------
__global__ __launch_bounds__(256) void fused_kernel(
        const float* __restrict__ pred_conf,
        const float* __restrict__ gt_conf,
        const float* __restrict__ pred_loc,
        const float* __restrict__ gt_loc,
        float* __restrict__ neg_loss,
        int* __restrict__ num_pos,
        float* __restrict__ pos_sum,
        float* __restrict__ loc_cnt,
        float* __restrict__ loc_sum) {
    const int b   = blockIdx.y;
    const int tid = threadIdx.x;

    if (blockIdx.x >= CBX) {
        // ================= loc part =================
        const int lb = blockIdx.x - CBX;
        const float4* pl = (const float4*)pred_loc;
        const float4* gl = (const float4*)gt_loc;
        float sum = 0.f, cnt = 0.f;
        #pragma unroll
        for (int j = 0; j < 8; ++j) {
            int n = lb * 2048 + j * 256 + tid;
            if (n < NN) {
                size_t idx = (size_t)b * NN + n;
                float4 p = pl[idx];
                float4 g = gl[idx];
                bool any = false;
                float pv[4] = {p.x, p.y, p.z, p.w};
                float gv[4] = {g.x, g.y, g.z, g.w};
                #pragma unroll
                for (int c = 0; c < 4; ++c) {
                    if (gv[c] != 0.f) {
                        any = true;
                        float d = fabsf(pv[c] - gv[c]);
                        sum += (d < 1.f) ? 0.5f * d * d : d - 0.5f;
                    }
                }
                if (any) cnt += 1.f;
            }
        }
        for (int o = 32; o; o >>= 1) {
            sum += __shfl_down(sum, o, 64);
            cnt += __shfl_down(cnt, o, 64);
        }
        if ((tid & 63) == 0) {
            atomicAdd(&loc_sum[b], sum);
            atomicAdd(&loc_cnt[b], cnt);
        }
        return;
    }

    // ================= conf part: 16 lanes per row, 4 rows per wave =================
    const int wave = tid >> 6;
    const int lane = tid & 63;
    const int sub  = lane & 15;          // lane within row
    const int rw   = lane >> 4;          // row within group (0..3)

    const int wid   = blockIdx.x * 4 + wave;      // 0..275
    const int strip = wid * STRIP;
    int ng = 0;
    if (strip < NN) {
        int nst = NN - strip; if (nst > STRIP) nst = STRIP;
        ng = (nst + 3) >> 2;
    }

    int   my_cnt = 0;
    float my_sum = 0.f;

    // current-group registers
    float cv0, cv1, cv2, cv3, cv4, cv5, cg0;
    int   c_n = 0; bool c_valid = false;

    // ---- prologue: issue group 0 loads ----
    if (ng > 0) {
        int n = strip + rw;
        c_valid = (n < NN);
        c_n = n;
        int ncl = c_valid ? n : (NN - 1);
        size_t base = ((size_t)b * NN + ncl) * CC;
        cv0 = pred_conf[base + sub +  0];
        cv1 = pred_conf[base + sub + 16];
        cv2 = pred_conf[base + sub + 32];
        cv3 = pred_conf[base + sub + 48];
        cv4 = pred_conf[base + sub + 64];
        cv5 = (sub == 0) ? pred_conf[base + 80] : -1e30f;
        cg0 = gt_conf[base];                         // uniform within 16 lanes
    }

    #pragma unroll
    for (int gi = 0; gi < GPW; ++gi) {
        if (gi >= ng) break;                         // wave-uniform

        // ---- issue next group's loads (overlap with compute below) ----
        float nv0, nv1, nv2, nv3, nv4, nv5, ngt0;
        int   n_n = 0; bool n_valid = false;
        if (gi + 1 < ng) {
            int n = strip + (gi + 1) * 4 + rw;
            n_valid = (n < NN);
            n_n = n;
            int ncl = n_valid ? n : (NN - 1);
            size_t base = ((size_t)b * NN + ncl) * CC;
            nv0 = pred_conf[base + sub +  0];
            nv1 = pred_conf[base + sub + 16];
            nv2 = pred_conf[base + sub + 32];
            nv3 = pred_conf[base + sub + 48];
            nv4 = pred_conf[base + sub + 64];
            nv5 = (sub == 0) ? pred_conf[base + 80] : -1e30f;
            ngt0 = gt_conf[base];
        }

        // ---- compute current group ----
        {
            size_t base = ((size_t)b * NN + (c_valid ? c_n : (NN - 1))) * CC;

            float m = fmaxf(fmaxf(fmaxf(cv0, cv1), fmaxf(cv2, cv3)), fmaxf(cv4, cv5));
            m = fmaxf(m, __shfl_xor(m, 1, 64));
            m = fmaxf(m, __shfl_xor(m, 2, 64));
            m = fmaxf(m, __shfl_xor(m, 4, 64));
            m = fmaxf(m, __shfl_xor(m, 8, 64));

            const bool pos = (cg0 == 0.f);           // uniform within 16 lanes

            // gather gt row for pos rows (rare ~3%): predicated loads
            float gv0 = 0.f, gv1 = 0.f, gv2 = 0.f, gv3 = 0.f, gv4 = 0.f, gv5 = 0.f;
            if (pos) {
                gv0 = gt_conf[base + sub +  0];
                gv1 = gt_conf[base + sub + 16];
                gv2 = gt_conf[base + sub + 32];
                gv3 = gt_conf[base + sub + 48];
                gv4 = gt_conf[base + sub + 64];
                gv5 = (sub == 0) ? gt_conf[base + 80] : 0.f;
            }

            float e = __expf(cv0 - m) + __expf(cv1 - m) + __expf(cv2 - m)
                    + __expf(cv3 - m) + __expf(cv4 - m);
            e += (sub == 0) ? __expf(cv5 - m) : 0.f;
            e += __shfl_xor(e, 1, 64);
            e += __shfl_xor(e, 2, 64);
            e += __shfl_xor(e, 4, 64);
            e += __shfl_xor(e, 8, 64);

            float x_sel = cv0;                       // f[0] on sub==0 (writer lane)
            if (pos) {
                float d = cv0 * gv0 + cv1 * gv1 + cv2 * gv2 + cv3 * gv3 + cv4 * gv4;
                d += (sub == 0) ? cv5 * gv5 : 0.f;
                d += __shfl_xor(d, 1, 64);
                d += __shfl_xor(d, 2, 64);
                d += __shfl_xor(d, 4, 64);
                d += __shfl_xor(d, 8, 64);
                x_sel = d;                           // pred at one-hot label
            }

            if (sub == 0 && c_valid) {
                const float loss = m + __logf(e) - x_sel;
                neg_loss[(size_t)b * NN + c_n] = pos ? 0.f : loss;
                if (pos) { my_cnt++; my_sum += loss; }
            }
        }

        // rotate prefetched group in (full unroll -> register renaming, no moves)
        cv0 = nv0; cv1 = nv1; cv2 = nv2; cv3 = nv3; cv4 = nv4; cv5 = nv5;
        cg0 = ngt0; c_n = n_n; c_valid = n_valid;
    }

    // writers are lanes 0,16,32,48 -> fold to lane 0
    my_sum += __shfl_down(my_sum, 32, 64);
    my_cnt += __shfl_down(my_cnt, 32, 64);
    my_sum += __shfl_down(my_sum, 16, 64);
    my_cnt += __shfl_down(my_cnt, 16, 64);
    if (lane == 0 && my_cnt) {
        atomicAdd(&num_pos[b], my_cnt);
        atomicAdd(&pos_sum[b], my_sum);
    }
}

// ---------------- per-batch radix select + finalize (atomic mean) ----------------
__global__ __launch_bounds__(256) void select_kernel(
        const float* __restrict__ neg_loss,
        const int*   __restrict__ num_pos,
        const float* __restrict__ pos_sum,
        const float* __restrict__ loc_cnt,
        const float* __restrict__ loc_sum,
        float* __restrict__ out) {
    const int b    = blockIdx.x;
    const int tid  = threadIdx.x;
    const int lane = tid & 63;
    __shared__ unsigned vals[NN];        // 34928 B
    __shared__ unsigned hist[256];
    __shared__ unsigned sh_prefix, sh_r;
    __shared__ float    s_part[4];

    #pragma unroll 4
    for (int i = tid; i < NN; i += 256)
        vals[i] = __float_as_uint(neg_loss[(size_t)b * NN + i]);

    const int np = num_pos[b];
    const int k  = min(3 * np, NN - 1);  // clip(int(num_neg), 0, N-1)
    if (tid == 0) { sh_prefix = 0u; sh_r = (unsigned)k; }
    __syncthreads();

    unsigned prefix_mask = 0u;
    for (int p = 3; p >= 0; --p) {
        const unsigned pref = sh_prefix;
        const unsigned r    = sh_r;
        hist[tid] = 0u;
        __syncthreads();

        // ballot-aggregated histogram: one atomic per distinct bin per wave
        for (int i0 = 0; i0 < NN; i0 += 256) {
            const int i = i0 + tid;
            const bool act = (i < NN) && ((vals[i] & prefix_mask) == pref);
            const unsigned v   = act ? vals[i] : 0u;
            const unsigned bin = (v >> (8 * p)) & 255u;
            unsigned long long mm = __ballot(act);
            #pragma unroll
            for (int bit = 0; bit < 8; ++bit) {
                unsigned long long s = __ballot(act && ((bin >> bit) & 1u));
                mm &= ((bin >> bit) & 1u) ? s : ~s;
            }
            if (act && ((mm & ((1ull << lane) - 1ull)) == 0ull))
                atomicAdd(&hist[bin], (unsigned)__popcll(mm));
        }
        __syncthreads();

        // wave-0 suffix scan over 256 bins (4 bins/lane) + bin pick
        if (tid < 64) {
            const unsigned h0 = hist[4 * tid + 0];
            const unsigned h1 = hist[4 * tid + 1];
            const unsigned h2 = hist[4 * tid + 2];
            const unsigned h3 = hist[4 * tid + 3];
            unsigned T = h0 + h1 + h2 + h3;
            #pragma unroll
            for (int off = 1; off < 64; off <<= 1) {
                unsigned t2 = __shfl_down(T, off, 64);
                if (tid + off < 64) T += t2;
            }
            unsigned Tn = __shfl_down(T, 1, 64);
            if (tid == 63) Tn = 0u;
            const unsigned S4 = Tn, S3 = S4 + h3, S2 = S3 + h2, S1 = S2 + h1, S0 = S1 + h0;
            int bin = -1; unsigned Slo = 0u;
            if      (S1 <= r && r < S0) { bin = 4 * tid + 0; Slo = S1; }
            else if (S2 <= r && r < S1) { bin = 4 * tid + 1; Slo = S2; }
            else if (S3 <= r && r < S2) { bin = 4 * tid + 2; Slo = S3; }
            else if (S4 <= r && r < S3) { bin = 4 * tid + 3; Slo = S4; }
            if (bin >= 0) {
                sh_r = r - Slo;
                sh_prefix = pref | ((unsigned)bin << (8 * p));
            }
        }
        __syncthreads();
        prefix_mask |= 0xFFu << (8 * p);
    }

    const float thresh = __uint_as_float(sh_prefix);   // exact (k+1)-th largest
    float s = 0.f;
    #pragma unroll 4
    for (int i = tid; i < NN; i += 256) {
        float v = __uint_as_float(vals[i]);
        if (v > thresh) s += v;                        // strict >, matches reference
    }
    for (int o = 32; o; o >>= 1) s += __shfl_down(s, o, 64);
    if (lane == 0) s_part[tid >> 6] = s;
    __syncthreads();
    if (tid == 0) {
        float neg_sum = s_part[0] + s_part[1] + s_part[2] + s_part[3];
        float npf = (float)np;
        float res = pos_sum[b] / npf + neg_sum / (3.0f * npf) + loc_sum[b] / loc_cnt[b];
        atomicAdd(out, res * (1.0f / BB));
    }
}

extern "C" void kernel_launch(void* const* d_in, const int* in_sizes, int n_in,
                              void* d_out, int out_size, void* d_ws, size_t ws_size,
                              hipStream_t stream) {
    const float* pred_conf = (const float*)d_in[0];
    const float* pred_loc  = (const float*)d_in[1];
    const float* gt_conf   = (const float*)d_in[2];
    const float* gt_loc    = (const float*)d_in[3];

    float* neg      = (float*)d_ws;                 // B*N floats
    int*   num_pos  = (int*)(neg + (size_t)BB * NN);
    float* pos_sum  = (float*)(num_pos + BB);
    float* loc_cnt  = pos_sum + BB;
    float* loc_sum  = loc_cnt + BB;

    init_kernel<<<1, 256, 0, stream>>>((unsigned*)num_pos, (float*)d_out);

    dim3 fgrid(CBX + LBX, BB);                      // 74 x 64
    fused_kernel<<<fgrid, 256, 0, stream>>>(pred_conf, gt_conf, pred_loc, gt_loc,
                                            neg, num_pos, pos_sum, loc_cnt, loc_sum);

    select_kernel<<<BB, 256, 0, stream>>>(neg, num_pos, pos_sum, loc_cnt, loc_sum,
                                          (float*)d_out);
}